// Round 9
// baseline (404.958 us; speedup 1.0000x reference)
//
#include <hip/hip_runtime.h>
#include <math.h>
#include <stdint.h>

// Problem constants: BS=16, SEQ=1024, NV=512, DM=256, K=8
#define BS 16
#define SEQ 1024
#define NV 512
#define DM 256
#define NK 8

// ---------------------------------------------------------------------------
// Module-global scratch. Every launch fully overwrites before reading
// (stream-ordered producer->consumer), so graph replay is self-contained.
// ---------------------------------------------------------------------------
__device__ double g_WC[NK * SEQ];                          // 64 KB
__device__ double g_Bk[NK];                                // 64 B
__device__ __align__(16) float g_Wt[SEQ * DM];             // 1 MB  [s][d]
__device__ __align__(16) float g_zp[4 * BS * NV * DM];     // 33.5 MB [kblk][b][v][d]
__device__ double g_nn2[BS * NV];                          // 64 KB
__device__ double g_Dp[8 * BS * NV * NK];                  // 4 MB [sc][b][v][k]
__device__ unsigned char g_bits[BS * NV];                  // 8 KB

// ---------------------------------------------------------------------------
// Exact JAX threefry2x32 (20 rounds), key = PRNGKey(7) = (0, 7).
// ---------------------------------------------------------------------------
__device__ __forceinline__ void threefry2x32_key7(uint32_t x0, uint32_t x1,
                                                  uint32_t& o0, uint32_t& o1) {
    const uint32_t k0 = 0u, k1 = 7u;
    const uint32_t k2 = k0 ^ k1 ^ 0x1BD11BDAu;
    uint32_t v0 = x0 + k0, v1 = x1 + k1;
#define TF_ROUND(r) { v0 += v1; v1 = (v1 << (r)) | (v1 >> (32 - (r))); v1 ^= v0; }
    TF_ROUND(13) TF_ROUND(15) TF_ROUND(26) TF_ROUND(6)
    v0 += k1; v1 += k2 + 1u;
    TF_ROUND(17) TF_ROUND(29) TF_ROUND(16) TF_ROUND(24)
    v0 += k2; v1 += k0 + 2u;
    TF_ROUND(13) TF_ROUND(15) TF_ROUND(26) TF_ROUND(6)
    v0 += k0; v1 += k1 + 3u;
    TF_ROUND(17) TF_ROUND(29) TF_ROUND(16) TF_ROUND(24)
    v0 += k1; v1 += k2 + 4u;
    TF_ROUND(13) TF_ROUND(15) TF_ROUND(26) TF_ROUND(6)
    v0 += k2; v1 += k0 + 5u;
#undef TF_ROUND
    o0 = v0; o1 = v1;
}

__device__ __forceinline__ float bits_to_uniform(uint32_t b) {
    return __uint_as_float((b >> 9) | 0x3F800000u) - 1.0f;
}

// ---------------------------------------------------------------------------
// Async global->LDS 16B copy (zero VGPR staging). LDS dest = wave-uniform
// base + lane*16; global source is PER-LANE.
// ---------------------------------------------------------------------------
__device__ __forceinline__ void cp16(const float* g, float* l) {
    __builtin_amdgcn_global_load_lds(
        (const __attribute__((address_space(1))) void*)g,
        (__attribute__((address_space(3))) void*)l,
        16, 0, 0);
}

// ---------------------------------------------------------------------------
// Merged W-transpose + prep (proven r5 form, plain [s][DM] g_Wt). 64 blocks.
// ---------------------------------------------------------------------------
__global__ __launch_bounds__(256) void prep_merged_kernel(
        const float* __restrict__ W, const float* __restrict__ bias,
        const float* __restrict__ ce) {
    __shared__ float tile[64][132];
    __shared__ double red[256];
    __shared__ double cen[256];
    const int t = threadIdx.x;
    const int bid = blockIdx.x;

    if (bid < 32) {
        const int s0 = (bid & 15) * 64;
        const int d0 = (bid >> 4) * 128;
#pragma unroll
        for (int p = 0; p < 32; ++p) {
            int lin = p * 256 + t;
            int d = lin >> 6, s = lin & 63;          // read coalesced over s
            tile[s][d] = W[(size_t)(d0 + d) * SEQ + s0 + s];
        }
        __syncthreads();
#pragma unroll
        for (int p = 0; p < 32; ++p) {
            int lin = p * 256 + t;
            int s = lin >> 7, d = lin & 127;         // write coalesced over d
            g_Wt[(size_t)(s0 + s) * DM + d0 + d] = tile[s][d];
        }
        return;
    }

    const int pid = bid - 32;
    const int k = pid >> 2;
    const int schunk = pid & 3;

    double c = (double)ce[k * DM + t];
    red[t] = c * c;
    __syncthreads();
    for (int off = 128; off > 0; off >>= 1) {
        if (t < off) red[t] += red[t + off];
        __syncthreads();
    }
    double nc = fmax(sqrt(red[0]), 1e-12);
    cen[t] = c / nc;
    __syncthreads();
    red[t] = (double)bias[t] * cen[t];
    __syncthreads();
    for (int off = 128; off > 0; off >>= 1) {
        if (t < off) red[t] += red[t + off];
        __syncthreads();
    }
    if (t == 0 && schunk == 0) g_Bk[k] = red[0];

    const int s = schunk * 256 + t;
    double acc = 0.0;
#pragma unroll 8
    for (int d = 0; d < DM; ++d)
        acc += cen[d] * (double)W[(size_t)d * SEQ + s];
    g_WC[(size_t)k * SEQ + s] = acc;
}

// ---------------------------------------------------------------------------
// GEMM v9: r3 geometry (64v x 256d tile, 8v x 8d thread tile, kblk=4
// cross-block K-split, 512 blocks = 2 blocks/CU) + T4 COUNTED-vmcnt
// 3-buffer pipeline. The r5/r8 nulls shared one trait: vmcnt drained to 0
// every chunk (implicitly or explicitly) -- the anti-pattern m218 measures
// at -38..-73%. Here:
//   iter c: STAGE(c+2) async -> buf[(c+2)%3]          (5 cp16 per wave)
//           s_waitcnt vmcnt(10)   == drain stage c only, keep c+1/c+2 flying
//           raw s_barrier          (NOT __syncthreads: that re-adds drain-0)
//           MAC(buf[c%3])
//           raw s_barrier          (stage c+3 at iter c+1 reuses buf c%3)
// Loads thus stay in flight across barriers for the whole kernel; the DMA
// tail leaves the critical path except in the 2-iter epilogue (5 -> 0).
// Uniform per-wave staging (4 W-row cp16 + 1 x cp16) keeps counted waits
// wave-uniform. sched_barrier(0) after every asm wait (rule #18).
// LDS: 3 x (16x256 + 16x64) x 4 = 60 KB -> 2 blocks/CU. VGPR ~120, no
// staging registers (r2/r4 spill trap structurally absent).
// FP order bit-identical to baseline: same single ascending-s acc chain
// per (kblk, v, d); KC 32->16 only sub-chunks the same sequence.
// ---------------------------------------------------------------------------
#define KC 16

__global__ __launch_bounds__(256) void gemm_kernel(
        const float* __restrict__ x) {
    __shared__ __align__(16) float xs[3][KC * 64];      // 3 x 4 KB
    __shared__ __align__(16) float wst[3][KC * 256];    // 3 x 16 KB

    const int t = threadIdx.x;
    const int kblk = blockIdx.x;    // 0..3
    const int vblk = blockIdx.y;    // 0..7
    const int b    = blockIdx.z;    // 0..15
    const int v0 = vblk * 64;
    const float* xb = x + (size_t)b * SEQ * NV + v0;

    const int tv8 = (t & 7) * 8;         // v offset (8 rows)
    const int td8 = (t >> 3) * 8;        // d offset (32 groups of 8)
    const int w = t >> 6;                // wave 0..3
    const int l = t & 63;                // lane

    // Per-lane DMA source offsets.
    const int l4  = l * 4;               // W: float offset within a 1 KB row
    const int xr4 = l >> 4;              // x: lane's row within 4-row group
    const int xc4 = (l & 15) * 4;        // x: lane's col offset
    const int wrow0 = w * 4;             // wave stages rows wrow0..wrow0+3

    float acc[8][8];
#pragma unroll
    for (int j = 0; j < 8; ++j)
#pragma unroll
        for (int i = 0; i < 8; ++i) acc[j][i] = 0.0f;

    const int sbeg = kblk * 256;

    // 5 cp16 per wave per stage: 4 x W (1 KB row each) + 1 x x (4 rows).
#define STAGE(BUF, C)                                                          \
    {                                                                          \
        const int S0 = sbeg + (C) * KC;                                        \
        _Pragma("unroll")                                                      \
        for (int j = 0; j < 4; ++j)                                            \
            cp16(&g_Wt[(size_t)(S0 + wrow0 + j) * DM + l4],                    \
                 &wst[BUF][(wrow0 + j) * 256]);                                \
        cp16(&xb[(size_t)(S0 + wrow0 + xr4) * NV + xc4],                       \
             &xs[BUF][wrow0 * 64]);                                            \
    }

#define MAC(BUF)                                                               \
    _Pragma("unroll")                                                          \
    for (int kk = 0; kk < KC; ++kk) {                                          \
        const float* xr = &xs[BUF][kk * 64 + tv8];                             \
        const float* wr = &wst[BUF][kk * 256 + td8];                           \
        float4 xv0 = *(const float4*)(xr);                                     \
        float4 xv1 = *(const float4*)(xr + 4);                                 \
        float4 wv0 = *(const float4*)(wr);                                     \
        float4 wv1 = *(const float4*)(wr + 4);                                 \
        float xv[8] = {xv0.x, xv0.y, xv0.z, xv0.w, xv1.x, xv1.y, xv1.z, xv1.w};\
        float wv[8] = {wv0.x, wv0.y, wv0.z, wv0.w, wv1.x, wv1.y, wv1.z, wv1.w};\
        _Pragma("unroll")                                                      \
        for (int j = 0; j < 8; ++j)                                            \
            _Pragma("unroll")                                                  \
            for (int i = 0; i < 8; ++i) acc[j][i] += xv[j] * wv[i];            \
    }

#define VMW(N)                                                                 \
    asm volatile("s_waitcnt vmcnt(" #N ")" ::: "memory");                      \
    __builtin_amdgcn_sched_barrier(0);

#define BAR()                                                                  \
    __builtin_amdgcn_s_barrier();                                              \
    __builtin_amdgcn_sched_barrier(0);

    // Prologue: two stages in flight.
    STAGE(0, 0)
    STAGE(1, 1)

    for (int c = 0; c < 14; ++c) {
        STAGE((c + 2) % 3, c + 2)
        VMW(10)                 // stage c landed; c+1, c+2 still flying
        BAR()
        MAC(c % 3)
        BAR()                   // protect buf c%3 from iter c+1's STAGE(c+3)
    }
    // Epilogue: c = 14, 15 (no new stages).
    VMW(5)                      // stage 14 landed; 15 flying
    BAR()
    MAC(2)                      // 14 % 3
    BAR()
    VMW(0)                      // stage 15 landed
    BAR()
    MAC(0)                      // 15 % 3

#undef STAGE
#undef MAC
#undef VMW
#undef BAR

    // Epilogue: fp32 z-partials for this kblk (same layout as baseline).
#pragma unroll
    for (int j = 0; j < 8; ++j) {
        size_t base = (size_t)kblk * (BS * NV * DM) +
                      ((size_t)b * NV + v0 + tv8 + j) * DM + td8;
#pragma unroll
        for (int m = 0; m < 8; m += 4)
            *(float4*)&g_zp[base + m] =
                make_float4(acc[j][m], acc[j][m + 1], acc[j][m + 2], acc[j][m + 3]);
    }
}

// ---------------------------------------------------------------------------
// Merged combine + dkern (proven r6/r8; verbatim). Blocks 0..511: combine.
// 512..1535: dkern.
// ---------------------------------------------------------------------------
__global__ __launch_bounds__(256) void cd_kernel(
        const float* __restrict__ bias, const float* __restrict__ x) {
    __shared__ double sm[3072];
    const int t = threadIdx.x;
    const int bid = blockIdx.x;

    if (bid < 512) {
        const int vg = bid >> 4;    // 0..31
        const int b  = bid & 15;    // 0..15
        const int vl = t >> 4, dg = t & 15;
        const int v = vg * 16 + vl;

        const size_t bvbase = ((size_t)b * NV + v) * DM + dg * 16;
        double sq = 0.0;
#pragma unroll
        for (int m = 0; m < 16; m += 4) {
            float4 p0 = *(const float4*)&g_zp[(size_t)0 * (BS * NV * DM) + bvbase + m];
            float4 p1 = *(const float4*)&g_zp[(size_t)1 * (BS * NV * DM) + bvbase + m];
            float4 p2 = *(const float4*)&g_zp[(size_t)2 * (BS * NV * DM) + bvbase + m];
            float4 p3 = *(const float4*)&g_zp[(size_t)3 * (BS * NV * DM) + bvbase + m];
            float4 bb = *(const float4*)&bias[dg * 16 + m];
            double z0 = (double)p0.x + (double)p1.x + (double)p2.x + (double)p3.x + (double)bb.x;
            double z1 = (double)p0.y + (double)p1.y + (double)p2.y + (double)p3.y + (double)bb.y;
            double z2 = (double)p0.z + (double)p1.z + (double)p2.z + (double)p3.z + (double)bb.z;
            double z3 = (double)p0.w + (double)p1.w + (double)p2.w + (double)p3.w + (double)bb.w;
            sq += z0 * z0 + z1 * z1 + z2 * z2 + z3 * z3;
        }
        sm[vl * 17 + dg] = sq;
        __syncthreads();
        if (dg == 0) {
            double s = 0.0;
#pragma unroll
            for (int i = 0; i < 16; ++i) s += sm[vl * 17 + i];
            g_nn2[b * NV + v] = s;
        }
        return;
    }

    const int did  = bid - 512;          // 0..1023
    const int vblk = did & 7;
    const int b    = (did >> 3) & 15;
    const int sc   = did >> 7;
    const int v0 = vblk * 64;
    const int ss = sc * 128;

    double* wcd = sm;                    // [NK][128]
    double* dw  = sm + 1024;             // [4][64][NK]

#pragma unroll
    for (int j = 0; j < 4; ++j) {
        int idx = j * 256 + t;
        wcd[idx] = g_WC[(size_t)(idx >> 7) * SEQ + ss + (idx & 127)];
    }
    __syncthreads();

    const int vl = t & 63, w = t >> 6;
    const float* xp = x + (size_t)b * SEQ * NV + v0 + vl;
    double D[NK];
#pragma unroll
    for (int k = 0; k < NK; ++k) D[k] = 0.0;
    const int sw = w * 32;
    for (int i = 0; i < 32; ++i) {
        int sl = sw + i;
        double xv = (double)xp[(size_t)(ss + sl) * NV];
#pragma unroll
        for (int k = 0; k < NK; ++k) D[k] += xv * wcd[k * 128 + sl];
    }
#pragma unroll
    for (int k = 0; k < NK; ++k) dw[(w * 64 + vl) * NK + k] = D[k];
    __syncthreads();

    const int v = t & 63, k2 = (t >> 6) * 2;
#pragma unroll
    for (int j = 0; j < 2; ++j) {
        int k = k2 + j;
        double s = dw[(0 * 64 + v) * NK + k] + dw[(1 * 64 + v) * NK + k] +
                   dw[(2 * 64 + v) * NK + k] + dw[(3 * 64 + v) * NK + k];
        g_Dp[(((size_t)sc * BS + b) * NV + v0 + v) * NK + k] = s;
    }
}

// ---------------------------------------------------------------------------
// Finalize (unchanged): sinkhorn softmax fp64, partitionable threefry, bits.
// ---------------------------------------------------------------------------
__global__ __launch_bounds__(256) void finalize_kernel() {
    const int bv = blockIdx.x * 256 + threadIdx.x;   // 0..8191
    double n = fmax(sqrt(g_nn2[bv]), 1e-12);

    double D[NK];
#pragma unroll
    for (int k = 0; k < NK; ++k) D[k] = g_Bk[k];
#pragma unroll
    for (int sc = 0; sc < 8; ++sc) {
#pragma unroll
        for (int k = 0; k < NK; ++k)
            D[k] += g_Dp[((size_t)sc * (BS * NV) + bv) * NK + k];
    }

    double p[NK], sum = 0.0;
#pragma unroll
    for (int k = 0; k < NK; ++k) {
        p[k] = exp((D[k] / n) / 0.05);
        sum += p[k];
    }
    unsigned int byte = 0;
#pragma unroll
    for (int k = 0; k < NK; ++k) {
        uint32_t i = (uint32_t)(k * (BS * NV) + bv);
        uint32_t y0, y1;
        threefry2x32_key7(0u, i, y0, y1);
        float u = bits_to_uniform(y0 ^ y1);
        if ((double)u < p[k] / sum) byte |= 1u << k;
    }
    g_bits[bv] = (unsigned char)byte;
}

// ---------------------------------------------------------------------------
// Write (unchanged): 268 MB broadcast, float4 stores — at HBM floor.
// ---------------------------------------------------------------------------
__global__ __launch_bounds__(256) void write_kernel(float* __restrict__ out) {
    const int t = threadIdx.x;
    const size_t r0 = (size_t)blockIdx.x * 8;
#pragma unroll
    for (int j = 0; j < 8; ++j) {
        size_t r = r0 + j;                      // r = (k*16+b)*512+v
        unsigned int bv = (unsigned int)(r & 8191u);
        unsigned int k  = (unsigned int)(r >> 13);
        float v = ((g_bits[bv] >> k) & 1u) ? 1.0f : 0.0f;
        float4 val = make_float4(v, v, v, v);
        ((float4*)(out + r * 1024))[t] = val;
    }
}

// ---------------------------------------------------------------------------
extern "C" void kernel_launch(void* const* d_in, const int* in_sizes, int n_in,
                              void* d_out, int out_size, void* d_ws, size_t ws_size,
                              hipStream_t stream) {
    const float* x    = (const float*)d_in[0];
    const float* W    = (const float*)d_in[1];
    const float* bias = (const float*)d_in[2];
    const float* ce   = (const float*)d_in[3];
    float* out = (float*)d_out;

    prep_merged_kernel<<<dim3(64), dim3(256), 0, stream>>>(W, bias, ce);
    gemm_kernel<<<dim3(4, 8, 16), dim3(256), 0, stream>>>(x);
    cd_kernel<<<dim3(1536), dim3(256), 0, stream>>>(bias, x);
    finalize_kernel<<<dim3(32), dim3(256), 0, stream>>>();
    write_kernel<<<dim3(8192), dim3(256), 0, stream>>>(out);
}

// Round 10
// 392.574 us; speedup vs baseline: 1.0315x; 1.0315x over previous
//
#include <hip/hip_runtime.h>
#include <math.h>
#include <stdint.h>

// Problem constants: BS=16, SEQ=1024, NV=512, DM=256, K=8
#define BS 16
#define SEQ 1024
#define NV 512
#define DM 256
#define NK 8

typedef __attribute__((ext_vector_type(8))) short bf16x8;
typedef __attribute__((ext_vector_type(4))) float f32x4;

// ---------------------------------------------------------------------------
// Module-global scratch. Every launch fully overwrites before reading.
// bf16 3-way splits: x transposed to [b][v][s] (s-major = A-fragment order),
// W kept [d][s] (s-major = B-fragment order).
// ---------------------------------------------------------------------------
__device__ double g_WC[NK * SEQ];                               // 64 KB
__device__ double g_Bk[NK];                                     // 64 B
__device__ __align__(16) unsigned short g_x0[BS * NV * SEQ];    // 16 MB
__device__ __align__(16) unsigned short g_x1[BS * NV * SEQ];    // 16 MB
__device__ __align__(16) unsigned short g_x2[BS * NV * SEQ];    // 16 MB
__device__ __align__(16) unsigned short g_w0[DM * SEQ];         // 512 KB
__device__ __align__(16) unsigned short g_w1[DM * SEQ];         // 512 KB
__device__ __align__(16) unsigned short g_w2[DM * SEQ];         // 512 KB
__device__ __align__(16) float g_zp[4 * BS * NV * DM];          // 33.5 MB
__device__ double g_nn2[BS * NV];                               // 64 KB
__device__ double g_Dp[8 * BS * NV * NK];                       // 4 MB
__device__ unsigned char g_bits[BS * NV];                       // 8 KB

// ---------------------------------------------------------------------------
// Exact JAX threefry2x32 (20 rounds), key = PRNGKey(7) = (0, 7).
// ---------------------------------------------------------------------------
__device__ __forceinline__ void threefry2x32_key7(uint32_t x0, uint32_t x1,
                                                  uint32_t& o0, uint32_t& o1) {
    const uint32_t k0 = 0u, k1 = 7u;
    const uint32_t k2 = k0 ^ k1 ^ 0x1BD11BDAu;
    uint32_t v0 = x0 + k0, v1 = x1 + k1;
#define TF_ROUND(r) { v0 += v1; v1 = (v1 << (r)) | (v1 >> (32 - (r))); v1 ^= v0; }
    TF_ROUND(13) TF_ROUND(15) TF_ROUND(26) TF_ROUND(6)
    v0 += k1; v1 += k2 + 1u;
    TF_ROUND(17) TF_ROUND(29) TF_ROUND(16) TF_ROUND(24)
    v0 += k2; v1 += k0 + 2u;
    TF_ROUND(13) TF_ROUND(15) TF_ROUND(26) TF_ROUND(6)
    v0 += k0; v1 += k1 + 3u;
    TF_ROUND(17) TF_ROUND(29) TF_ROUND(16) TF_ROUND(24)
    v0 += k1; v1 += k2 + 4u;
    TF_ROUND(13) TF_ROUND(15) TF_ROUND(26) TF_ROUND(6)
    v0 += k2; v1 += k0 + 5u;
#undef TF_ROUND
    o0 = v0; o1 = v1;
}

__device__ __forceinline__ float bits_to_uniform(uint32_t b) {
    return __uint_as_float((b >> 9) | 0x3F800000u) - 1.0f;
}

// bf16 split helpers (RNE; residuals exact by Sterbenz).
__device__ __forceinline__ unsigned short f2bf(float f) {
    uint32_t u = __float_as_uint(f);
    return (unsigned short)((u + 0x7FFFu + ((u >> 16) & 1u)) >> 16);
}
__device__ __forceinline__ float bf2f(unsigned short h) {
    return __uint_as_float(((uint32_t)h) << 16);
}
__device__ __forceinline__ void split3(float f, unsigned short& h0,
                                       unsigned short& h1, unsigned short& h2) {
    h0 = f2bf(f);
    float r1 = f - bf2f(h0);
    h1 = f2bf(r1);
    float r2 = r1 - bf2f(h1);
    h2 = f2bf(r2);
}

// Async global->LDS 16B copy: LDS dest = wave-uniform base + lane*16,
// global source PER-LANE.
__device__ __forceinline__ void cp16s(const unsigned short* g, unsigned short* l) {
    __builtin_amdgcn_global_load_lds(
        (const __attribute__((address_space(1))) void*)g,
        (__attribute__((address_space(3))) void*)l,
        16, 0, 0);
}

// ---------------------------------------------------------------------------
// Prep: blocks 0..31 = WC/Bk in fp64 (proven verbatim); blocks 32..95 =
// W 3-way bf16 split, [d][s] layout kept (elementwise, 16 elems/thread).
// ---------------------------------------------------------------------------
__global__ __launch_bounds__(256) void prep_kernel(
        const float* __restrict__ W, const float* __restrict__ bias,
        const float* __restrict__ ce) {
    __shared__ double red[256];
    __shared__ double cen[256];
    const int t = threadIdx.x;
    const int bid = blockIdx.x;

    if (bid >= 32) {
        const int base = (bid - 32) * 4096 + t * 16;
        uint32_t p0[8], p1[8], p2[8];
#pragma unroll
        for (int i = 0; i < 16; ++i) {
            unsigned short h0, h1, h2;
            split3(W[base + i], h0, h1, h2);
            if (i & 1) {
                p0[i >> 1] |= (uint32_t)h0 << 16;
                p1[i >> 1] |= (uint32_t)h1 << 16;
                p2[i >> 1] |= (uint32_t)h2 << 16;
            } else {
                p0[i >> 1] = h0; p1[i >> 1] = h1; p2[i >> 1] = h2;
            }
        }
        *(uint4*)&g_w0[base]     = make_uint4(p0[0], p0[1], p0[2], p0[3]);
        *(uint4*)&g_w0[base + 8] = make_uint4(p0[4], p0[5], p0[6], p0[7]);
        *(uint4*)&g_w1[base]     = make_uint4(p1[0], p1[1], p1[2], p1[3]);
        *(uint4*)&g_w1[base + 8] = make_uint4(p1[4], p1[5], p1[6], p1[7]);
        *(uint4*)&g_w2[base]     = make_uint4(p2[0], p2[1], p2[2], p2[3]);
        *(uint4*)&g_w2[base + 8] = make_uint4(p2[4], p2[5], p2[6], p2[7]);
        return;
    }

    const int k = bid >> 2;
    const int schunk = bid & 3;

    double c = (double)ce[k * DM + t];
    red[t] = c * c;
    __syncthreads();
    for (int off = 128; off > 0; off >>= 1) {
        if (t < off) red[t] += red[t + off];
        __syncthreads();
    }
    double nc = fmax(sqrt(red[0]), 1e-12);
    cen[t] = c / nc;
    __syncthreads();
    red[t] = (double)bias[t] * cen[t];
    __syncthreads();
    for (int off = 128; off > 0; off >>= 1) {
        if (t < off) red[t] += red[t + off];
        __syncthreads();
    }
    if (t == 0 && schunk == 0) g_Bk[k] = red[0];

    const int s = schunk * 256 + t;
    double acc = 0.0;
#pragma unroll 8
    for (int d = 0; d < DM; ++d)
        acc += cen[d] * (double)W[(size_t)d * SEQ + s];
    g_WC[(size_t)k * SEQ + s] = acc;
}

// ---------------------------------------------------------------------------
// x transpose + 3-way bf16 split: x[b][s][v] fp32 -> g_x{0,1,2}[b][v][s] bf16.
// 64s x 64v LDS tiles; read coalesced over v, write 32B-chunks per row.
// Grid (stile16 * vtile8, b16) = 2048 blocks.
// ---------------------------------------------------------------------------
__global__ __launch_bounds__(256) void xsplit_kernel(const float* __restrict__ x) {
    __shared__ float tile[64][65];
    const int t = threadIdx.x;
    const int stile = blockIdx.x >> 3, vtile = blockIdx.x & 7;
    const int b = blockIdx.y;
    const int s0 = stile * 64, v0 = vtile * 64;
    const float* xb = x + ((size_t)b * SEQ + s0) * NV + v0;

#pragma unroll
    for (int p = 0; p < 16; ++p) {
        int lin = p * 256 + t;
        int sl = lin >> 6, vv = lin & 63;
        tile[sl][vv] = xb[(size_t)sl * NV + vv];
    }
    __syncthreads();

    const int vr = t >> 2, g = t & 3;
    const size_t obase = ((size_t)b * NV + v0 + vr) * SEQ + s0 + g * 16;
    uint32_t p0[8], p1[8], p2[8];
#pragma unroll
    for (int i = 0; i < 16; ++i) {
        unsigned short h0, h1, h2;
        split3(tile[g * 16 + i][vr], h0, h1, h2);
        if (i & 1) {
            p0[i >> 1] |= (uint32_t)h0 << 16;
            p1[i >> 1] |= (uint32_t)h1 << 16;
            p2[i >> 1] |= (uint32_t)h2 << 16;
        } else {
            p0[i >> 1] = h0; p1[i >> 1] = h1; p2[i >> 1] = h2;
        }
    }
    *(uint4*)&g_x0[obase]     = make_uint4(p0[0], p0[1], p0[2], p0[3]);
    *(uint4*)&g_x0[obase + 8] = make_uint4(p0[4], p0[5], p0[6], p0[7]);
    *(uint4*)&g_x1[obase]     = make_uint4(p1[0], p1[1], p1[2], p1[3]);
    *(uint4*)&g_x1[obase + 8] = make_uint4(p1[4], p1[5], p1[6], p1[7]);
    *(uint4*)&g_x2[obase]     = make_uint4(p2[0], p2[1], p2[2], p2[3]);
    *(uint4*)&g_x2[obase + 8] = make_uint4(p2[4], p2[5], p2[6], p2[7]);
}

// ---------------------------------------------------------------------------
// GEMM v10: MFMA bf16 3-split emulation (G10: this is a K=1024 dot product;
// fp32-VALU exhausted at 130us vs 41us floor across 4 schedule-nulls).
// z = (x0+x1+x2)(w0+w1+w2), keeping 6 products >= 2^-18: error ~1e-7|z| =
// same order as the proven fp32-partial baseline; fp64 combine unchanged.
// Block: 64v x 128d x 256s, 256 thr / 4 waves (wave w owns d 32w..32w+32),
// grid (kblk4*dblk2, vblk8, b16) = 1024 blocks = 4 blocks/CU = 4 waves/SIMD.
// LDS 36 KB single-buffered, staged by cp16 with XOR k-group swizzle
// (linear dest + inverse-swizzled per-lane source + swizzled read, rule #21)
// so the 64B-stride fragment reads are bank-uniform instead of 8-way.
// Fragment layouts (guide SS3, m89-verified C/D):
//   A[m=l&15][k=(l>>4)*8+i]  from xT tile rows = v, 8 consecutive s = b128
//   B[k=(l>>4)*8+i][n=l&15]  from W  tile rows = d, 8 consecutive s = b128
//   D col=l&15 (d), row=(l>>4)*4+reg (v)
// Per chunk/wave: 9 cp16 stage, 18 ds_read_b128, 48 MFMA (6 products x 4m x
// 2n), accumulated small->large into acc[mb][nb] (K-loop recipe: same acc).
// ---------------------------------------------------------------------------
__global__ __launch_bounds__(256) void gemm_kernel() {
    __shared__ __align__(16) unsigned short xs3[3][64 * 32];    // 12 KB
    __shared__ __align__(16) unsigned short ws3[3][128 * 32];   // 24 KB

    const int t = threadIdx.x;
    const int kblk = blockIdx.x & 3;     // 0..3
    const int dblk = blockIdx.x >> 2;    // 0..1
    const int vblk = blockIdx.y;         // 0..7
    const int b    = blockIdx.z;         // 0..15
    const int v0 = vblk * 64, d0 = dblk * 128;
    const int w = t >> 6, l = t & 63;

    // Staging: lane l fills LDS row (l>>2) of its 16-row group, slot l&3.
    // Content for slot S of row R is k-group S^(R&3)  (XOR swizzle).
    const int srow = l >> 2;
    const int sk8  = ((l & 3) ^ ((l >> 2) & 3)) * 8;   // src k-elem offset
    // Fragment read: row l&15 (+16*sub), k-group l>>4 lives at slot
    // (l>>4)^(row&3) = (l>>4)^(l&3).
    const int rrow = l & 15;
    const int rsl  = ((l >> 4) ^ (l & 3)) * 8;

    const size_t xbase = ((size_t)b * NV + v0) * SEQ;
    const size_t wbase = (size_t)d0 * SEQ;
    const unsigned short* xsrc[3] = {g_x0 + xbase, g_x1 + xbase, g_x2 + xbase};
    const unsigned short* wsrc[3] = {g_w0 + wbase, g_w1 + wbase, g_w2 + wbase};

    f32x4 acc[4][2];
#pragma unroll
    for (int mb = 0; mb < 4; ++mb)
#pragma unroll
        for (int nb = 0; nb < 2; ++nb) acc[mb][nb] = (f32x4){0.f, 0.f, 0.f, 0.f};

    for (int c = 0; c < 8; ++c) {
        const int s0 = kblk * 256 + c * 32;
        __syncthreads();   // prior chunk's fragment reads complete
        // Stage (per wave): x rows w*16..+15 (3 cp16), W rows w*32..+31 (6).
#pragma unroll
        for (int sp = 0; sp < 3; ++sp) {
            cp16s(&xsrc[sp][(size_t)(w * 16 + srow) * SEQ + s0 + sk8],
                  &xs3[sp][w * 16 * 32]);
            cp16s(&wsrc[sp][(size_t)(w * 32 + srow) * SEQ + s0 + sk8],
                  &ws3[sp][w * 32 * 32]);
            cp16s(&wsrc[sp][(size_t)(w * 32 + 16 + srow) * SEQ + s0 + sk8],
                  &ws3[sp][(w * 32 + 16) * 32]);
        }
        __syncthreads();   // drains DMA (compiler vmcnt(0) before barrier)

        bf16x8 a[3][4], bb[3][2];
#pragma unroll
        for (int sp = 0; sp < 3; ++sp) {
#pragma unroll
            for (int mb = 0; mb < 4; ++mb)
                a[sp][mb] = *(const bf16x8*)&xs3[sp][(mb * 16 + rrow) * 32 + rsl];
#pragma unroll
            for (int nb = 0; nb < 2; ++nb)
                bb[sp][nb] = *(const bf16x8*)
                    &ws3[sp][(w * 32 + nb * 16 + rrow) * 32 + rsl];
        }
#pragma unroll
        for (int mb = 0; mb < 4; ++mb)
#pragma unroll
            for (int nb = 0; nb < 2; ++nb) {
                f32x4 v = acc[mb][nb];
                v = __builtin_amdgcn_mfma_f32_16x16x32_bf16(a[1][mb], bb[1][nb], v, 0, 0, 0);
                v = __builtin_amdgcn_mfma_f32_16x16x32_bf16(a[0][mb], bb[2][nb], v, 0, 0, 0);
                v = __builtin_amdgcn_mfma_f32_16x16x32_bf16(a[2][mb], bb[0][nb], v, 0, 0, 0);
                v = __builtin_amdgcn_mfma_f32_16x16x32_bf16(a[0][mb], bb[1][nb], v, 0, 0, 0);
                v = __builtin_amdgcn_mfma_f32_16x16x32_bf16(a[1][mb], bb[0][nb], v, 0, 0, 0);
                v = __builtin_amdgcn_mfma_f32_16x16x32_bf16(a[0][mb], bb[0][nb], v, 0, 0, 0);
                acc[mb][nb] = v;
            }
    }

    // Epilogue: fp32 z-partials, layout identical to baseline g_zp.
    const int rowb = (l >> 4) * 4;
#pragma unroll
    for (int mb = 0; mb < 4; ++mb)
#pragma unroll
        for (int nb = 0; nb < 2; ++nb) {
            const int d = d0 + w * 32 + nb * 16 + (l & 15);
#pragma unroll
            for (int r = 0; r < 4; ++r) {
                const int v = v0 + mb * 16 + rowb + r;
                g_zp[(size_t)kblk * (BS * NV * DM) +
                     ((size_t)b * NV + v) * DM + d] = acc[mb][nb][r];
            }
        }
}

// ---------------------------------------------------------------------------
// Merged combine + dkern (proven; verbatim). Blocks 0..511: combine
// (fp64 sum of 4 kblk partials + bias, nn2). 512..1535: dkern (fp64).
// ---------------------------------------------------------------------------
__global__ __launch_bounds__(256) void cd_kernel(
        const float* __restrict__ bias, const float* __restrict__ x) {
    __shared__ double sm[3072];
    const int t = threadIdx.x;
    const int bid = blockIdx.x;

    if (bid < 512) {
        const int vg = bid >> 4;
        const int b  = bid & 15;
        const int vl = t >> 4, dg = t & 15;
        const int v = vg * 16 + vl;

        const size_t bvbase = ((size_t)b * NV + v) * DM + dg * 16;
        double sq = 0.0;
#pragma unroll
        for (int m = 0; m < 16; m += 4) {
            float4 p0 = *(const float4*)&g_zp[(size_t)0 * (BS * NV * DM) + bvbase + m];
            float4 p1 = *(const float4*)&g_zp[(size_t)1 * (BS * NV * DM) + bvbase + m];
            float4 p2 = *(const float4*)&g_zp[(size_t)2 * (BS * NV * DM) + bvbase + m];
            float4 p3 = *(const float4*)&g_zp[(size_t)3 * (BS * NV * DM) + bvbase + m];
            float4 bb = *(const float4*)&bias[dg * 16 + m];
            double z0 = (double)p0.x + (double)p1.x + (double)p2.x + (double)p3.x + (double)bb.x;
            double z1 = (double)p0.y + (double)p1.y + (double)p2.y + (double)p3.y + (double)bb.y;
            double z2 = (double)p0.z + (double)p1.z + (double)p2.z + (double)p3.z + (double)bb.z;
            double z3 = (double)p0.w + (double)p1.w + (double)p2.w + (double)p3.w + (double)bb.w;
            sq += z0 * z0 + z1 * z1 + z2 * z2 + z3 * z3;
        }
        sm[vl * 17 + dg] = sq;
        __syncthreads();
        if (dg == 0) {
            double s = 0.0;
#pragma unroll
            for (int i = 0; i < 16; ++i) s += sm[vl * 17 + i];
            g_nn2[b * NV + v] = s;
        }
        return;
    }

    const int did  = bid - 512;
    const int vblk = did & 7;
    const int b    = (did >> 3) & 15;
    const int sc   = did >> 7;
    const int v0 = vblk * 64;
    const int ss = sc * 128;

    double* wcd = sm;
    double* dw  = sm + 1024;

#pragma unroll
    for (int j = 0; j < 4; ++j) {
        int idx = j * 256 + t;
        wcd[idx] = g_WC[(size_t)(idx >> 7) * SEQ + ss + (idx & 127)];
    }
    __syncthreads();

    const int vl = t & 63, w = t >> 6;
    const float* xp = x + (size_t)b * SEQ * NV + v0 + vl;
    double D[NK];
#pragma unroll
    for (int k = 0; k < NK; ++k) D[k] = 0.0;
    const int sw = w * 32;
    for (int i = 0; i < 32; ++i) {
        int sl = sw + i;
        double xv = (double)xp[(size_t)(ss + sl) * NV];
#pragma unroll
        for (int k = 0; k < NK; ++k) D[k] += xv * wcd[k * 128 + sl];
    }
#pragma unroll
    for (int k = 0; k < NK; ++k) dw[(w * 64 + vl) * NK + k] = D[k];
    __syncthreads();

    const int v = t & 63, k2 = (t >> 6) * 2;
#pragma unroll
    for (int j = 0; j < 2; ++j) {
        int k = k2 + j;
        double s = dw[(0 * 64 + v) * NK + k] + dw[(1 * 64 + v) * NK + k] +
                   dw[(2 * 64 + v) * NK + k] + dw[(3 * 64 + v) * NK + k];
        g_Dp[(((size_t)sc * BS + b) * NV + v0 + v) * NK + k] = s;
    }
}

// ---------------------------------------------------------------------------
// Finalize (unchanged): sinkhorn softmax fp64, partitionable threefry, bits.
// ---------------------------------------------------------------------------
__global__ __launch_bounds__(256) void finalize_kernel() {
    const int bv = blockIdx.x * 256 + threadIdx.x;
    double n = fmax(sqrt(g_nn2[bv]), 1e-12);

    double D[NK];
#pragma unroll
    for (int k = 0; k < NK; ++k) D[k] = g_Bk[k];
#pragma unroll
    for (int sc = 0; sc < 8; ++sc) {
#pragma unroll
        for (int k = 0; k < NK; ++k)
            D[k] += g_Dp[((size_t)sc * (BS * NV) + bv) * NK + k];
    }

    double p[NK], sum = 0.0;
#pragma unroll
    for (int k = 0; k < NK; ++k) {
        p[k] = exp((D[k] / n) / 0.05);
        sum += p[k];
    }
    unsigned int byte = 0;
#pragma unroll
    for (int k = 0; k < NK; ++k) {
        uint32_t i = (uint32_t)(k * (BS * NV) + bv);
        uint32_t y0, y1;
        threefry2x32_key7(0u, i, y0, y1);
        float u = bits_to_uniform(y0 ^ y1);
        if ((double)u < p[k] / sum) byte |= 1u << k;
    }
    g_bits[bv] = (unsigned char)byte;
}

// ---------------------------------------------------------------------------
// Write (unchanged): 268 MB broadcast, float4 stores — at HBM floor.
// ---------------------------------------------------------------------------
__global__ __launch_bounds__(256) void write_kernel(float* __restrict__ out) {
    const int t = threadIdx.x;
    const size_t r0 = (size_t)blockIdx.x * 8;
#pragma unroll
    for (int j = 0; j < 8; ++j) {
        size_t r = r0 + j;
        unsigned int bv = (unsigned int)(r & 8191u);
        unsigned int k  = (unsigned int)(r >> 13);
        float v = ((g_bits[bv] >> k) & 1u) ? 1.0f : 0.0f;
        float4 val = make_float4(v, v, v, v);
        ((float4*)(out + r * 1024))[t] = val;
    }
}

// ---------------------------------------------------------------------------
extern "C" void kernel_launch(void* const* d_in, const int* in_sizes, int n_in,
                              void* d_out, int out_size, void* d_ws, size_t ws_size,
                              hipStream_t stream) {
    const float* x    = (const float*)d_in[0];
    const float* W    = (const float*)d_in[1];
    const float* bias = (const float*)d_in[2];
    const float* ce   = (const float*)d_in[3];
    float* out = (float*)d_out;

    prep_kernel<<<dim3(96), dim3(256), 0, stream>>>(W, bias, ce);
    xsplit_kernel<<<dim3(128, 16), dim3(256), 0, stream>>>(x);
    gemm_kernel<<<dim3(8, 8, 16), dim3(256), 0, stream>>>();
    cd_kernel<<<dim3(1536), dim3(256), 0, stream>>>(bias, x);
    finalize_kernel<<<dim3(32), dim3(256), 0, stream>>>();
    write_kernel<<<dim3(8192), dim3(256), 0, stream>>>(out);
}